// Round 16
// baseline (659.825 us; speedup 1.0000x reference)
//
#include <hip/hip_runtime.h>
#include <cstdint>

// Problem constants
#define NROWS   131072
#define NUNITS  256
#define KTOT    512          // INPUT_DIM + UNITS
#define BM      64           // rows per block
#define THREADS 256

typedef float f32x4  __attribute__((ext_vector_type(4)));
typedef short bf16x8 __attribute__((ext_vector_type(8)));

__device__ __forceinline__ short f2bf(float x) {
    unsigned u = __float_as_uint(x);
    u += 0x7FFFu + ((u >> 16) & 1u);   // round-to-nearest-even
    return (short)(u >> 16);
}

// W [512][1024] fp32 -> Wws [16][1024][32] bf16 (B-fragment order, L2-resident).
// A wave's B-frag load (16 cols x 16B granule) = one coalesced 1 KiB region.
__global__ void convert_W_kernel(const float* __restrict__ W, short* __restrict__ Wws) {
    int i = blockIdx.x * 256 + threadIdx.x;       // 0 .. 524287
    int k = i >> 10;
    int c = i & 1023;
    Wws[((size_t)(k >> 5) << 15) + ((size_t)c << 5) + (k & 31)] = f2bf(W[i]);
}

// Main: ZERO LDS, ZERO barriers -- fully wave-independent (the one structure
// the R7-R15 ladder showed is not barrier-convoy-limited).
// Grid 8192 = 2048 row-tiles x 4 u-tiles, XCD-swizzled (the 4 u-tiles sharing
// a row panel land adjacent on one XCD; panel working set is 16KB/phase ->
// all intra-block and cross-block A duplication is L2-served; HBM reads x/h once).
// Block: 256 threads = 4 waves; wave w owns cols ut*64 + w*16 + lr for all 4
// gates -> acc[4][4], lane-local fused LSTM epilogue.
// Phase p (fully unrolled, 16 phases of k=32):
//   per m: 2x global_load_dwordx4 fp32 A (16 rows x 128B windows; lanes
//          {l,l+16,l+32,l+48} fill each window) + 4 cvt_pk -> af[m]
//   4x coalesced dwordx4 B-frag loads from L2-resident Wws -> bfr
//   16 MFMA
// No waits besides compiler per-value vmcnt; compiler pipelines loads across
// phases freely (no barrier blocks it); 12 independent waves/CU hide latency.
// __launch_bounds__(256,3): 168-VGPR cap -> no spill (R13 lesson), 3 blocks/CU.
__global__ void __launch_bounds__(THREADS, 3)
lstm_main_kernel(const float* __restrict__ x, const float* __restrict__ h_prev,
                 const float* __restrict__ c_prev, const float* __restrict__ bias,
                 const float* __restrict__ pi, const float* __restrict__ pf,
                 const float* __restrict__ po, const short* __restrict__ Wws,
                 float* __restrict__ out) {
    const int bid = blockIdx.x;
    const int swz = (bid & 7) * 1024 + (bid >> 3);   // bijective, 8192 % 8 == 0
    const int ut  = swz & 3;
    const int rt  = swz >> 2;
    const int row0 = rt * BM;

    const int t    = threadIdx.x;
    const int lane = t & 63;
    const int w    = t >> 6;             // wave 0..3 = col quarter
    const int lr   = lane & 15;
    const int hi   = lane >> 4;          // k-granule 0..3

    // ---- A fragment source byte-offsets (per m), within x / h_prev ----
    // af[m]: row = row0 + m*16 + lr, k-window = (p&7)*128B + hi*32B
    int aoff[4];
    #pragma unroll
    for (int m = 0; m < 4; ++m)
        aoff[m] = ((row0 + m * 16 + lr) << 10) + (hi << 5);

    // ---- B fragment base: col = g*256 + ut*64 + w*16 + lr, granule hi ----
    const int ucol = ut * 64 + w * 16 + lr;
    const short* wfrag = Wws + ((size_t)ucol << 5) + hi * 8;   // + p*32768 + g*8192

    f32x4 acc[4][4];
    #pragma unroll
    for (int m = 0; m < 4; ++m)
        #pragma unroll
        for (int g = 0; g < 4; ++g)
            acc[m][g] = (f32x4){0.f, 0.f, 0.f, 0.f};

    #pragma unroll
    for (int p = 0; p < 16; ++p) {
        const char* Abase = (const char*)(p < 8 ? x : h_prev) + ((p & 7) << 7);

        bf16x8 af[4];
        #pragma unroll
        for (int m = 0; m < 4; ++m) {
            f32x4 lo  = *(const f32x4*)(Abase + aoff[m]);
            f32x4 hi4 = *(const f32x4*)(Abase + aoff[m] + 16);
            unsigned v0, v1, v2, v3;
            asm("v_cvt_pk_bf16_f32 %0, %1, %2" : "=v"(v0) : "v"(lo[0]),  "v"(lo[1]));
            asm("v_cvt_pk_bf16_f32 %0, %1, %2" : "=v"(v1) : "v"(lo[2]),  "v"(lo[3]));
            asm("v_cvt_pk_bf16_f32 %0, %1, %2" : "=v"(v2) : "v"(hi4[0]), "v"(hi4[1]));
            asm("v_cvt_pk_bf16_f32 %0, %1, %2" : "=v"(v3) : "v"(hi4[2]), "v"(hi4[3]));
            unsigned uu[4] = {v0, v1, v2, v3};
            af[m] = *(bf16x8*)uu;
        }

        const short* wp = wfrag + ((size_t)p << 15);
        bf16x8 bfr[4];
        #pragma unroll
        for (int g = 0; g < 4; ++g)
            bfr[g] = *(const bf16x8*)(wp + g * 8192);   // coalesced L2 reg load

        #pragma unroll
        for (int g = 0; g < 4; ++g)
            #pragma unroll
            for (int m = 0; m < 4; ++m)
                acc[m][g] = __builtin_amdgcn_mfma_f32_16x16x32_bf16(af[m], bfr[g], acc[m][g], 0, 0, 0);
    }

    // ---- fused LSTM epilogue (lane-local: all 4 gates in acc[m][0..3]) ----
    const size_t HS = (size_t)NROWS * NUNITS;
    const int u = ucol;
    const float bi = bias[u],       bfg = bias[256 + u];
    const float bc = bias[512 + u], bo  = bias[768 + u];
    const float ppi = pi[u], ppf = pf[u], ppo = po[u];
    #pragma unroll
    for (int m = 0; m < 4; ++m) {
        #pragma unroll
        for (int r = 0; r < 4; ++r) {
            const int row = row0 + m * 16 + hi * 4 + r;
            const size_t o = (size_t)row * NUNITS + u;
            const float cp = c_prev[o];
            float zi = acc[m][0][r] + bi  + ppi * cp;
            float zf = acc[m][1][r] + bfg + ppf * cp;
            float zc = acc[m][2][r] + bc;
            float zo = acc[m][3][r] + bo  + ppo * cp;
            float ig = 1.f / (1.f + __expf(-zi));
            float fg = 1.f / (1.f + __expf(-zf));
            float og = 1.f / (1.f + __expf(-zo));
            zc = fminf(fmaxf(zc, -30.f), 30.f);
            float e2 = __expf(2.f * zc);
            float chat = (e2 - 1.f) / (e2 + 1.f);
            float c  = fg * cp + ig * chat;
            float ccl = fminf(fmaxf(c, -30.f), 30.f);
            float e3 = __expf(2.f * ccl);
            float th = (e3 - 1.f) / (e3 + 1.f);
            float h  = og * th;
            out[o]          = h;
            out[HS + o]     = h;
            out[2 * HS + o] = c;
        }
    }
}

extern "C" void kernel_launch(void* const* d_in, const int* in_sizes, int n_in,
                              void* d_out, int out_size, void* d_ws, size_t ws_size,
                              hipStream_t stream) {
    const float* x  = (const float*)d_in[0];
    const float* h  = (const float*)d_in[1];
    const float* c  = (const float*)d_in[2];
    const float* W  = (const float*)d_in[3];
    const float* b  = (const float*)d_in[4];
    const float* pi = (const float*)d_in[5];
    const float* pf = (const float*)d_in[6];
    const float* po = (const float*)d_in[7];
    float* out = (float*)d_out;

    short* Wws = (short*)d_ws;            // 1 MiB bf16 copy of W in B-frag order

    hipLaunchKernelGGL(convert_W_kernel, dim3(2048), dim3(256), 0, stream, W, Wws);
    hipLaunchKernelGGL(lstm_main_kernel, dim3(NROWS / BM * 4), dim3(THREADS), 0, stream,
                       x, h, c, b, pi, pf, po, Wws, out);
}

// Round 17
// 438.622 us; speedup vs baseline: 1.5043x; 1.5043x over previous
//
#include <hip/hip_runtime.h>
#include <cstdint>

// Problem constants
#define NROWS   131072
#define NUNITS  256
#define KTOT    512          // INPUT_DIM + UNITS
#define BM      128          // rows per block
#define THREADS 512

typedef float f32x4  __attribute__((ext_vector_type(4)));
typedef short bf16x8 __attribute__((ext_vector_type(8)));

__device__ __forceinline__ short f2bf(float x) {
    unsigned u = __float_as_uint(x);
    u += 0x7FFFu + ((u >> 16) & 1u);   // round-to-nearest-even
    return (short)(u >> 16);
}

// W [512][1024] fp32 -> Wws [16][1024][32] bf16 (B-fragment order, L2-resident).
__global__ void convert_W_kernel(const float* __restrict__ W, short* __restrict__ Wws) {
    int i = blockIdx.x * 256 + threadIdx.x;       // 0 .. 524287
    int k = i >> 10;
    int c = i & 1023;
    Wws[((size_t)(k >> 5) << 15) + ((size_t)c << 5) + (k & 31)] = f2bf(W[i]);
}

// Main (R12 structure, best measured, + final-phase c_prev prefetch + nt I/O):
// grid 4096 = 1024 row-tiles x 4 u-tiles (XCD-swizzled -> A panel L2-reused).
// Block: 128 rows x 64 u x 4 gates. 8 waves = 2 row-halves x 4 col-quarters;
// wave tile 64x64, acc[4][4] (all 4 gates lane-local -> fused epilogue).
// Phase p (fully unrolled, 16 phases of BK=32, phase 15 peeled):
//   dmaB(p+1) [2 gload_lds] -> glbA(p+2) [2 dwordx4 fp32] ->
//   writeA(p+1) [auto vmcnt<=4; 4 cvt_pk + ds_write_b128, BEFORE compute] ->
//   compute(p) [8 ds_read_b128 + 16 MFMA, setprio] ->
//   s_waitcnt vmcnt(2) lgkmcnt(0)  [retire B(p+1); glbA(p+2) stays in flight]
//   s_barrier
// Peeled phase 15: after the final vmcnt(0)+barrier (zero outstanding VMEM),
// issue 16 nontemporal c_prev loads -> overlap compute(15) + cover HBM latency
// before the epilogue's transcendental chain. Out stores are nontemporal
// (402 MB streaming, no reuse) so L2/L3 keeps the x/h panels hot.
// Layouts: R7/R12-verified conflict-free (64B row stride, granule XOR
// (row>>1)&3; B swizzle on gload_lds SOURCE (rule #21), A on per-lane ds_write).
__global__ void __launch_bounds__(THREADS, 4)
lstm_main_kernel(const float* __restrict__ x, const float* __restrict__ h_prev,
                 const float* __restrict__ c_prev, const float* __restrict__ bias,
                 const float* __restrict__ pi, const float* __restrict__ pf,
                 const float* __restrict__ po, const short* __restrict__ Wws,
                 float* __restrict__ out) {
    __shared__ short Ab[2][4096];   // 2 x 8 KB  bf16 A tiles [128r][32k] swizzled
    __shared__ short Bb[2][8192];   // 2 x 16 KB bf16 B tiles

    const int bid = blockIdx.x;
    const int swz = (bid & 7) * 512 + (bid >> 3);
    const int ut  = swz & 3;
    const int rt  = swz >> 2;
    const int row0 = rt * BM;

    const int t    = threadIdx.x;
    const int lane = t & 63;
    const int w    = t >> 6;
    const int lr   = lane & 15;
    const int hi   = lane >> 4;          // k-granule 0..3
    const int rh   = w >> 2;             // row half 0..1
    const int q    = w & 3;              // col quarter 0..3
    const int u    = ut * 64 + q * 16 + lr;   // this lane's unit column

    // ---- A staging: thread t -> row t>>2, source granule g = t&3 (8 fp32) ----
    const int arow = t >> 2, ag = t & 3;
    const int avoff = ((row0 + arow) * 256 + ag * 8) * 4;          // bytes into x/h
    const int awr   = arow * 32 + ((ag ^ ((arow >> 1) & 3)) * 8);  // LDS shorts

    // ---- B DMA source byte-offsets (R7 scheme, 0 conflicts measured) ----
    const int u0  = (t >> 2) & 63;
    const int bg0 = t >> 8;              // 0..1
    const int bsw = ((t & 3) ^ ((t >> 3) & 3)) * 8;
    const int bvoff0 = (((bg0    ) * 256 + ut * 64 + u0) * 32 + bsw) * 2;
    const int bvoff1 = (((bg0 + 2) * 256 + ut * 64 + u0) * 32 + bsw) * 2;

    // ---- fragment read offsets (shorts): swizzle matches write side ----
    const int sw   = (hi ^ ((lr >> 1) & 3)) * 8;
    const int aoff = (rh * 64 + lr) * 32 + sw;           // + m*512
    const int boff = (q * 16 + lr) * 32 + sw;            // + g*2048

    f32x4 acc[4][4];
    #pragma unroll
    for (int m = 0; m < 4; ++m)
        #pragma unroll
        for (int g = 0; g < 4; ++g)
            acc[m][g] = (f32x4){0.f, 0.f, 0.f, 0.f};

    f32x4 sreg[2][2];                    // two in-flight A register sets (parity)
    auto glbA = [&](int p) {
        const char* base = (const char*)(p < 8 ? x : h_prev) + ((p & 7) << 7);
        sreg[p & 1][0] = *(const f32x4*)(base + avoff);
        sreg[p & 1][1] = *(const f32x4*)(base + avoff + 16);
    };
    auto writeA = [&](int p) {
        const f32x4* s = sreg[p & 1];
        unsigned u0_, u1_, u2_, u3_;
        asm("v_cvt_pk_bf16_f32 %0, %1, %2" : "=v"(u0_) : "v"(s[0][0]), "v"(s[0][1]));
        asm("v_cvt_pk_bf16_f32 %0, %1, %2" : "=v"(u1_) : "v"(s[0][2]), "v"(s[0][3]));
        asm("v_cvt_pk_bf16_f32 %0, %1, %2" : "=v"(u2_) : "v"(s[1][0]), "v"(s[1][1]));
        asm("v_cvt_pk_bf16_f32 %0, %1, %2" : "=v"(u3_) : "v"(s[1][2]), "v"(s[1][3]));
        int4 v = make_int4((int)u0_, (int)u1_, (int)u2_, (int)u3_);
        *(int4*)&Ab[p & 1][awr] = v;
    };
    auto dmaB = [&](int p) {
        const char* wb = (const char*)Wws + ((size_t)p << 16);
        short* dst = &Bb[p & 1][0];
        __builtin_amdgcn_global_load_lds(
            (const __attribute__((address_space(1))) uint32_t*)(const void*)(wb + bvoff0),
            (__attribute__((address_space(3))) uint32_t*)(void*)(dst + t * 8), 16, 0, 0);
        __builtin_amdgcn_global_load_lds(
            (const __attribute__((address_space(1))) uint32_t*)(const void*)(wb + bvoff1),
            (__attribute__((address_space(3))) uint32_t*)(void*)(dst + 4096 + t * 8), 16, 0, 0);
    };
    auto compute = [&](int p) {
        const short* A = &Ab[p & 1][0];
        const short* B = &Bb[p & 1][0];
        bf16x8 af[4], bfr[4];
        #pragma unroll
        for (int m = 0; m < 4; ++m)
            af[m] = *(const bf16x8*)&A[aoff + m * 512];
        #pragma unroll
        for (int g = 0; g < 4; ++g)
            bfr[g] = *(const bf16x8*)&B[boff + g * 2048];
        __builtin_amdgcn_s_setprio(1);
        #pragma unroll
        for (int g = 0; g < 4; ++g)
            #pragma unroll
            for (int m = 0; m < 4; ++m)
                acc[m][g] = __builtin_amdgcn_mfma_f32_16x16x32_bf16(af[m], bfr[g], acc[m][g], 0, 0, 0);
        __builtin_amdgcn_s_setprio(0);
    };

    // ---- prologue: A(0) published; B(0) done; glbA(1) in flight ----
    glbA(0);
    dmaB(0);
    glbA(1);
    writeA(0);                            // auto-wait retires glbA(0)
    asm volatile("s_waitcnt vmcnt(2) lgkmcnt(0)" ::: "memory");  // B(0) done; glbA(1) in flight
    __builtin_amdgcn_s_barrier();

    #pragma unroll
    for (int p = 0; p < 15; ++p) {
        dmaB(p + 1);                      // B lookahead 1 (L2-resident, cheap)
        if (p <= 13) glbA(p + 2);         // A lookahead 2 (HBM ~900cyc covered)
        writeA(p + 1);                    // auto vmcnt<=4: B(p+1), glbA(p+2) stay in flight
        compute(p);
        if (p <= 13) {
            asm volatile("s_waitcnt vmcnt(2) lgkmcnt(0)" ::: "memory");  // retire B(p+1)
            __builtin_amdgcn_s_barrier();
        } else {
            asm volatile("s_waitcnt vmcnt(0) lgkmcnt(0)" ::: "memory");
            __builtin_amdgcn_s_barrier();
        }
    }

    // ---- peeled phase 15: prefetch c_prev (nt) under the last MFMA cluster ----
    float cpv[16];
    #pragma unroll
    for (int m = 0; m < 4; ++m)
        #pragma unroll
        for (int r = 0; r < 4; ++r) {
            const int row = row0 + rh * 64 + m * 16 + hi * 4 + r;
            cpv[m * 4 + r] = __builtin_nontemporal_load(&c_prev[(size_t)row * NUNITS + u]);
        }
    compute(15);

    // ---- fused LSTM epilogue (lane-local: all 4 gates in acc[m][0..3]) ----
    const size_t HS = (size_t)NROWS * NUNITS;
    const float bi = bias[u],       bfg = bias[256 + u];
    const float bc = bias[512 + u], bo  = bias[768 + u];
    const float ppi = pi[u], ppf = pf[u], ppo = po[u];
    #pragma unroll
    for (int m = 0; m < 4; ++m) {
        #pragma unroll
        for (int r = 0; r < 4; ++r) {
            const int row = row0 + rh * 64 + m * 16 + hi * 4 + r;
            const size_t o = (size_t)row * NUNITS + u;
            const float cp = cpv[m * 4 + r];
            float zi = acc[m][0][r] + bi  + ppi * cp;
            float zf = acc[m][1][r] + bfg + ppf * cp;
            float zc = acc[m][2][r] + bc;
            float zo = acc[m][3][r] + bo  + ppo * cp;
            float ig = 1.f / (1.f + __expf(-zi));
            float fg = 1.f / (1.f + __expf(-zf));
            float og = 1.f / (1.f + __expf(-zo));
            zc = fminf(fmaxf(zc, -30.f), 30.f);
            float e2 = __expf(2.f * zc);
            float chat = (e2 - 1.f) / (e2 + 1.f);
            float c  = fg * cp + ig * chat;
            float ccl = fminf(fmaxf(c, -30.f), 30.f);
            float e3 = __expf(2.f * ccl);
            float th = (e3 - 1.f) / (e3 + 1.f);
            float h  = og * th;
            __builtin_nontemporal_store(h, &out[o]);
            __builtin_nontemporal_store(h, &out[HS + o]);
            __builtin_nontemporal_store(c, &out[2 * HS + o]);
        }
    }
}

extern "C" void kernel_launch(void* const* d_in, const int* in_sizes, int n_in,
                              void* d_out, int out_size, void* d_ws, size_t ws_size,
                              hipStream_t stream) {
    const float* x  = (const float*)d_in[0];
    const float* h  = (const float*)d_in[1];
    const float* c  = (const float*)d_in[2];
    const float* W  = (const float*)d_in[3];
    const float* b  = (const float*)d_in[4];
    const float* pi = (const float*)d_in[5];
    const float* pf = (const float*)d_in[6];
    const float* po = (const float*)d_in[7];
    float* out = (float*)d_out;

    short* Wws = (short*)d_ws;            // 1 MiB bf16 copy of W in B-frag order

    hipLaunchKernelGGL(convert_W_kernel, dim3(2048), dim3(256), 0, stream, W, Wws);
    hipLaunchKernelGGL(lstm_main_kernel, dim3(NROWS / BM * 4), dim3(THREADS), 0, stream,
                       x, h, c, b, pi, pf, po, Wws, out);
}

// Round 18
// 417.806 us; speedup vs baseline: 1.5793x; 1.0498x over previous
//
#include <hip/hip_runtime.h>
#include <cstdint>

// Problem constants
#define NROWS   131072
#define NUNITS  256
#define KTOT    512          // INPUT_DIM + UNITS
#define BM      128          // rows per block
#define THREADS 512

typedef float f32x4  __attribute__((ext_vector_type(4)));
typedef short bf16x8 __attribute__((ext_vector_type(8)));

__device__ __forceinline__ short f2bf(float x) {
    unsigned u = __float_as_uint(x);
    u += 0x7FFFu + ((u >> 16) & 1u);   // round-to-nearest-even
    return (short)(u >> 16);
}

// W [512][1024] fp32 -> Wws [16][1024][32] bf16 (B-fragment order, L2-resident).
__global__ void convert_W_kernel(const float* __restrict__ W, short* __restrict__ Wws) {
    int i = blockIdx.x * 256 + threadIdx.x;       // 0 .. 524287
    int k = i >> 10;
    int c = i & 1023;
    Wws[((size_t)(k >> 5) << 15) + ((size_t)c << 5) + (k & 31)] = f2bf(W[i]);
}

// Main (R12 structure -- measured best, 302us total -- plus final-phase c_prev
// prefetch with NORMAL loads; all nt hints removed after R17's WRITE-doubling).
// grid 4096 = 1024 row-tiles x 4 u-tiles (XCD-swizzled -> A panel L2-reused).
// Block: 128 rows x 64 u x 4 gates. 8 waves = 2 row-halves x 4 col-quarters;
// wave tile 64x64, acc[4][4] (all 4 gates lane-local -> fused epilogue).
// Phase p (fully unrolled, 16 phases of BK=32, phase 15 peeled):
//   dmaB(p+1) [2 gload_lds] -> glbA(p+2) [2 dwordx4 fp32] ->
//   writeA(p+1) [auto vmcnt<=4; 4 cvt_pk + ds_write_b128, BEFORE compute] ->
//   compute(p) [8 ds_read_b128 + 16 MFMA, setprio] ->
//   s_waitcnt vmcnt(2) lgkmcnt(0)  [retire B(p+1); glbA(p+2) stays in flight]
//   s_barrier
// Peeled phase 15: after the final vmcnt(0)+barrier (zero outstanding VMEM),
// issue 16 plain c_prev loads -> overlap compute(15), cover HBM latency before
// the epilogue's transcendental chain. Plain stores (L2 write-coalesced).
// Layouts: R7/R12-verified conflict-free (64B row stride, granule XOR
// (row>>1)&3; B swizzle on gload_lds SOURCE (rule #21), A on per-lane ds_write).
__global__ void __launch_bounds__(THREADS, 4)
lstm_main_kernel(const float* __restrict__ x, const float* __restrict__ h_prev,
                 const float* __restrict__ c_prev, const float* __restrict__ bias,
                 const float* __restrict__ pi, const float* __restrict__ pf,
                 const float* __restrict__ po, const short* __restrict__ Wws,
                 float* __restrict__ out) {
    __shared__ short Ab[2][4096];   // 2 x 8 KB  bf16 A tiles [128r][32k] swizzled
    __shared__ short Bb[2][8192];   // 2 x 16 KB bf16 B tiles

    const int bid = blockIdx.x;
    const int swz = (bid & 7) * 512 + (bid >> 3);
    const int ut  = swz & 3;
    const int rt  = swz >> 2;
    const int row0 = rt * BM;

    const int t    = threadIdx.x;
    const int lane = t & 63;
    const int w    = t >> 6;
    const int lr   = lane & 15;
    const int hi   = lane >> 4;          // k-granule 0..3
    const int rh   = w >> 2;             // row half 0..1
    const int q    = w & 3;              // col quarter 0..3
    const int u    = ut * 64 + q * 16 + lr;   // this lane's unit column

    // ---- A staging: thread t -> row t>>2, source granule g = t&3 (8 fp32) ----
    const int arow = t >> 2, ag = t & 3;
    const int avoff = ((row0 + arow) * 256 + ag * 8) * 4;          // bytes into x/h
    const int awr   = arow * 32 + ((ag ^ ((arow >> 1) & 3)) * 8);  // LDS shorts

    // ---- B DMA source byte-offsets (R7 scheme, 0 conflicts measured) ----
    const int u0  = (t >> 2) & 63;
    const int bg0 = t >> 8;              // 0..1
    const int bsw = ((t & 3) ^ ((t >> 3) & 3)) * 8;
    const int bvoff0 = (((bg0    ) * 256 + ut * 64 + u0) * 32 + bsw) * 2;
    const int bvoff1 = (((bg0 + 2) * 256 + ut * 64 + u0) * 32 + bsw) * 2;

    // ---- fragment read offsets (shorts): swizzle matches write side ----
    const int sw   = (hi ^ ((lr >> 1) & 3)) * 8;
    const int aoff = (rh * 64 + lr) * 32 + sw;           // + m*512
    const int boff = (q * 16 + lr) * 32 + sw;            // + g*2048

    f32x4 acc[4][4];
    #pragma unroll
    for (int m = 0; m < 4; ++m)
        #pragma unroll
        for (int g = 0; g < 4; ++g)
            acc[m][g] = (f32x4){0.f, 0.f, 0.f, 0.f};

    f32x4 sreg[2][2];                    // two in-flight A register sets (parity)
    auto glbA = [&](int p) {
        const char* base = (const char*)(p < 8 ? x : h_prev) + ((p & 7) << 7);
        sreg[p & 1][0] = *(const f32x4*)(base + avoff);
        sreg[p & 1][1] = *(const f32x4*)(base + avoff + 16);
    };
    auto writeA = [&](int p) {
        const f32x4* s = sreg[p & 1];
        unsigned u0_, u1_, u2_, u3_;
        asm("v_cvt_pk_bf16_f32 %0, %1, %2" : "=v"(u0_) : "v"(s[0][0]), "v"(s[0][1]));
        asm("v_cvt_pk_bf16_f32 %0, %1, %2" : "=v"(u1_) : "v"(s[0][2]), "v"(s[0][3]));
        asm("v_cvt_pk_bf16_f32 %0, %1, %2" : "=v"(u2_) : "v"(s[1][0]), "v"(s[1][1]));
        asm("v_cvt_pk_bf16_f32 %0, %1, %2" : "=v"(u3_) : "v"(s[1][2]), "v"(s[1][3]));
        int4 v = make_int4((int)u0_, (int)u1_, (int)u2_, (int)u3_);
        *(int4*)&Ab[p & 1][awr] = v;
    };
    auto dmaB = [&](int p) {
        const char* wb = (const char*)Wws + ((size_t)p << 16);
        short* dst = &Bb[p & 1][0];
        __builtin_amdgcn_global_load_lds(
            (const __attribute__((address_space(1))) uint32_t*)(const void*)(wb + bvoff0),
            (__attribute__((address_space(3))) uint32_t*)(void*)(dst + t * 8), 16, 0, 0);
        __builtin_amdgcn_global_load_lds(
            (const __attribute__((address_space(1))) uint32_t*)(const void*)(wb + bvoff1),
            (__attribute__((address_space(3))) uint32_t*)(void*)(dst + 4096 + t * 8), 16, 0, 0);
    };
    auto compute = [&](int p) {
        const short* A = &Ab[p & 1][0];
        const short* B = &Bb[p & 1][0];
        bf16x8 af[4], bfr[4];
        #pragma unroll
        for (int m = 0; m < 4; ++m)
            af[m] = *(const bf16x8*)&A[aoff + m * 512];
        #pragma unroll
        for (int g = 0; g < 4; ++g)
            bfr[g] = *(const bf16x8*)&B[boff + g * 2048];
        __builtin_amdgcn_s_setprio(1);
        #pragma unroll
        for (int g = 0; g < 4; ++g)
            #pragma unroll
            for (int m = 0; m < 4; ++m)
                acc[m][g] = __builtin_amdgcn_mfma_f32_16x16x32_bf16(af[m], bfr[g], acc[m][g], 0, 0, 0);
        __builtin_amdgcn_s_setprio(0);
    };

    // ---- prologue: A(0) published; B(0) done; glbA(1) in flight ----
    glbA(0);
    dmaB(0);
    glbA(1);
    writeA(0);                            // auto-wait retires glbA(0)
    asm volatile("s_waitcnt vmcnt(2) lgkmcnt(0)" ::: "memory");  // B(0) done; glbA(1) in flight
    __builtin_amdgcn_s_barrier();

    #pragma unroll
    for (int p = 0; p < 15; ++p) {
        dmaB(p + 1);                      // B lookahead 1 (L2-resident, cheap)
        if (p <= 13) glbA(p + 2);         // A lookahead 2 (HBM ~900cyc covered)
        writeA(p + 1);                    // auto vmcnt<=4: B(p+1), glbA(p+2) stay in flight
        compute(p);
        if (p <= 13) {
            asm volatile("s_waitcnt vmcnt(2) lgkmcnt(0)" ::: "memory");  // retire B(p+1)
            __builtin_amdgcn_s_barrier();
        } else {
            asm volatile("s_waitcnt vmcnt(0) lgkmcnt(0)" ::: "memory");
            __builtin_amdgcn_s_barrier();
        }
    }

    // ---- peeled phase 15: prefetch c_prev under the last MFMA cluster ----
    float cpv[16];
    #pragma unroll
    for (int m = 0; m < 4; ++m)
        #pragma unroll
        for (int r = 0; r < 4; ++r) {
            const int row = row0 + rh * 64 + m * 16 + hi * 4 + r;
            cpv[m * 4 + r] = c_prev[(size_t)row * NUNITS + u];
        }
    compute(15);

    // ---- fused LSTM epilogue (lane-local: all 4 gates in acc[m][0..3]) ----
    const size_t HS = (size_t)NROWS * NUNITS;
    const float bi = bias[u],       bfg = bias[256 + u];
    const float bc = bias[512 + u], bo  = bias[768 + u];
    const float ppi = pi[u], ppf = pf[u], ppo = po[u];
    #pragma unroll
    for (int m = 0; m < 4; ++m) {
        #pragma unroll
        for (int r = 0; r < 4; ++r) {
            const int row = row0 + rh * 64 + m * 16 + hi * 4 + r;
            const size_t o = (size_t)row * NUNITS + u;
            const float cp = cpv[m * 4 + r];
            float zi = acc[m][0][r] + bi  + ppi * cp;
            float zf = acc[m][1][r] + bfg + ppf * cp;
            float zc = acc[m][2][r] + bc;
            float zo = acc[m][3][r] + bo  + ppo * cp;
            float ig = 1.f / (1.f + __expf(-zi));
            float fg = 1.f / (1.f + __expf(-zf));
            float og = 1.f / (1.f + __expf(-zo));
            zc = fminf(fmaxf(zc, -30.f), 30.f);
            float e2 = __expf(2.f * zc);
            float chat = (e2 - 1.f) / (e2 + 1.f);
            float c  = fg * cp + ig * chat;
            float ccl = fminf(fmaxf(c, -30.f), 30.f);
            float e3 = __expf(2.f * ccl);
            float th = (e3 - 1.f) / (e3 + 1.f);
            float h  = og * th;
            out[o]          = h;
            out[HS + o]     = h;
            out[2 * HS + o] = c;
        }
    }
}

extern "C" void kernel_launch(void* const* d_in, const int* in_sizes, int n_in,
                              void* d_out, int out_size, void* d_ws, size_t ws_size,
                              hipStream_t stream) {
    const float* x  = (const float*)d_in[0];
    const float* h  = (const float*)d_in[1];
    const float* c  = (const float*)d_in[2];
    const float* W  = (const float*)d_in[3];
    const float* b  = (const float*)d_in[4];
    const float* pi = (const float*)d_in[5];
    const float* pf = (const float*)d_in[6];
    const float* po = (const float*)d_in[7];
    float* out = (float*)d_out;

    short* Wws = (short*)d_ws;            // 1 MiB bf16 copy of W in B-frag order

    hipLaunchKernelGGL(convert_W_kernel, dim3(2048), dim3(256), 0, stream, W, Wws);
    hipLaunchKernelGGL(lstm_main_kernel, dim3(NROWS / BM * 4), dim3(THREADS), 0, stream,
                       x, h, c, b, pi, pf, po, Wws, out);
}

// Round 19
// 298.589 us; speedup vs baseline: 2.2098x; 1.3993x over previous
//
#include <hip/hip_runtime.h>
#include <cstdint>

// Problem constants
#define NROWS   131072
#define NUNITS  256
#define KTOT    512          // INPUT_DIM + UNITS
#define BM      128          // rows per block
#define THREADS 512

typedef float f32x4  __attribute__((ext_vector_type(4)));
typedef short bf16x8 __attribute__((ext_vector_type(8)));

__device__ __forceinline__ short f2bf(float x) {
    unsigned u = __float_as_uint(x);
    u += 0x7FFFu + ((u >> 16) & 1u);   // round-to-nearest-even
    return (short)(u >> 16);
}

// W [512][1024] fp32 -> Wws [16][1024][32] bf16 (B-fragment order, L2-resident).
__global__ void convert_W_kernel(const float* __restrict__ W, short* __restrict__ Wws) {
    int i = blockIdx.x * 256 + threadIdx.x;       // 0 .. 524287
    int k = i >> 10;
    int c = i & 1023;
    Wws[((size_t)(k >> 5) << 15) + ((size_t)c << 5) + (k & 31)] = f2bf(W[i]);
}

// Main: R12 EXACT REVERT -- the measured-best configuration (302 us total).
// grid 4096 = 1024 row-tiles x 4 u-tiles (XCD-swizzled: the 4 u-tiles of a
// row panel co-locate on one XCD -> fp32 A panel HBM-fetched once, L2-served).
// Block: 128 rows x 64 u x 4 gates. 8 waves = 2 row-halves x 4 col-quarters;
// wave tile 64x64, acc[4][4] (all 4 gates lane-local -> fused epilogue).
// Phase p (fully unrolled, 16 phases of BK=32):
//   dmaB(p+1) [2 gload_lds] -> glbA(p+2) [2 dwordx4 fp32] ->
//   writeA(p+1) [auto vmcnt<=4; 4 cvt_pk + ds_write_b128, BEFORE compute] ->
//   compute(p) [8 ds_read_b128 + 16 MFMA, setprio] ->
//   s_waitcnt vmcnt(2) lgkmcnt(0)  [retire B(p+1); glbA(p+2) stays in flight]
//   s_barrier
// Epilogue: c_prev loaded inline per gate group; plain stores (L2-merged --
// R17/R18 showed nt stores and burst prefetch both double WRITE_SIZE).
// Layouts: R7/R12-verified conflict-free (64B row stride, granule XOR
// (row>>1)&3; B swizzle on gload_lds SOURCE (rule #21), A on per-lane ds_write).
__global__ void __launch_bounds__(THREADS, 4)
lstm_main_kernel(const float* __restrict__ x, const float* __restrict__ h_prev,
                 const float* __restrict__ c_prev, const float* __restrict__ bias,
                 const float* __restrict__ pi, const float* __restrict__ pf,
                 const float* __restrict__ po, const short* __restrict__ Wws,
                 float* __restrict__ out) {
    __shared__ short Ab[2][4096];   // 2 x 8 KB  bf16 A tiles [128r][32k] swizzled
    __shared__ short Bb[2][8192];   // 2 x 16 KB bf16 B tiles

    const int bid = blockIdx.x;
    const int swz = (bid & 7) * 512 + (bid >> 3);
    const int ut  = swz & 3;
    const int rt  = swz >> 2;
    const int row0 = rt * BM;

    const int t    = threadIdx.x;
    const int lane = t & 63;
    const int w    = t >> 6;
    const int lr   = lane & 15;
    const int hi   = lane >> 4;          // k-granule 0..3
    const int rh   = w >> 2;             // row half 0..1
    const int q    = w & 3;              // col quarter 0..3

    // ---- A staging: thread t -> row t>>2, source granule g = t&3 (8 fp32) ----
    const int arow = t >> 2, ag = t & 3;
    const int avoff = ((row0 + arow) * 256 + ag * 8) * 4;          // bytes into x/h
    const int awr   = arow * 32 + ((ag ^ ((arow >> 1) & 3)) * 8);  // LDS shorts

    // ---- B DMA source byte-offsets (R7 scheme, 0 conflicts measured) ----
    const int u0  = (t >> 2) & 63;
    const int bg0 = t >> 8;              // 0..1
    const int bsw = ((t & 3) ^ ((t >> 3) & 3)) * 8;
    const int bvoff0 = (((bg0    ) * 256 + ut * 64 + u0) * 32 + bsw) * 2;
    const int bvoff1 = (((bg0 + 2) * 256 + ut * 64 + u0) * 32 + bsw) * 2;

    // ---- fragment read offsets (shorts): swizzle matches write side ----
    const int sw   = (hi ^ ((lr >> 1) & 3)) * 8;
    const int aoff = (rh * 64 + lr) * 32 + sw;           // + m*512
    const int boff = (q * 16 + lr) * 32 + sw;            // + g*2048

    f32x4 acc[4][4];
    #pragma unroll
    for (int m = 0; m < 4; ++m)
        #pragma unroll
        for (int g = 0; g < 4; ++g)
            acc[m][g] = (f32x4){0.f, 0.f, 0.f, 0.f};

    f32x4 sreg[2][2];                    // two in-flight A register sets (parity)
    auto glbA = [&](int p) {
        const char* base = (const char*)(p < 8 ? x : h_prev) + ((p & 7) << 7);
        sreg[p & 1][0] = *(const f32x4*)(base + avoff);
        sreg[p & 1][1] = *(const f32x4*)(base + avoff + 16);
    };
    auto writeA = [&](int p) {
        const f32x4* s = sreg[p & 1];
        unsigned u0_, u1_, u2_, u3_;
        asm("v_cvt_pk_bf16_f32 %0, %1, %2" : "=v"(u0_) : "v"(s[0][0]), "v"(s[0][1]));
        asm("v_cvt_pk_bf16_f32 %0, %1, %2" : "=v"(u1_) : "v"(s[0][2]), "v"(s[0][3]));
        asm("v_cvt_pk_bf16_f32 %0, %1, %2" : "=v"(u2_) : "v"(s[1][0]), "v"(s[1][1]));
        asm("v_cvt_pk_bf16_f32 %0, %1, %2" : "=v"(u3_) : "v"(s[1][2]), "v"(s[1][3]));
        int4 v = make_int4((int)u0_, (int)u1_, (int)u2_, (int)u3_);
        *(int4*)&Ab[p & 1][awr] = v;
    };
    auto dmaB = [&](int p) {
        const char* wb = (const char*)Wws + ((size_t)p << 16);
        short* dst = &Bb[p & 1][0];
        __builtin_amdgcn_global_load_lds(
            (const __attribute__((address_space(1))) uint32_t*)(const void*)(wb + bvoff0),
            (__attribute__((address_space(3))) uint32_t*)(void*)(dst + t * 8), 16, 0, 0);
        __builtin_amdgcn_global_load_lds(
            (const __attribute__((address_space(1))) uint32_t*)(const void*)(wb + bvoff1),
            (__attribute__((address_space(3))) uint32_t*)(void*)(dst + 4096 + t * 8), 16, 0, 0);
    };
    auto compute = [&](int p) {
        const short* A = &Ab[p & 1][0];
        const short* B = &Bb[p & 1][0];
        bf16x8 af[4], bfr[4];
        #pragma unroll
        for (int m = 0; m < 4; ++m)
            af[m] = *(const bf16x8*)&A[aoff + m * 512];
        #pragma unroll
        for (int g = 0; g < 4; ++g)
            bfr[g] = *(const bf16x8*)&B[boff + g * 2048];
        __builtin_amdgcn_s_setprio(1);
        #pragma unroll
        for (int g = 0; g < 4; ++g)
            #pragma unroll
            for (int m = 0; m < 4; ++m)
                acc[m][g] = __builtin_amdgcn_mfma_f32_16x16x32_bf16(af[m], bfr[g], acc[m][g], 0, 0, 0);
        __builtin_amdgcn_s_setprio(0);
    };

    // ---- prologue: A(0) published; B(0) done; glbA(1) in flight ----
    glbA(0);
    dmaB(0);
    glbA(1);
    writeA(0);                            // auto-wait retires glbA(0)
    asm volatile("s_waitcnt vmcnt(2) lgkmcnt(0)" ::: "memory");  // B(0) done; glbA(1) in flight
    __builtin_amdgcn_s_barrier();

    #pragma unroll
    for (int p = 0; p < 16; ++p) {
        if (p <= 14) dmaB(p + 1);         // B lookahead 1 (L2-resident, cheap)
        if (p <= 13) glbA(p + 2);         // A lookahead 2 (HBM ~900cyc covered)
        if (p <= 14) writeA(p + 1);       // auto vmcnt<=4: B(p+1), glbA(p+2) stay in flight
        compute(p);
        if (p <= 13) {
            asm volatile("s_waitcnt vmcnt(2) lgkmcnt(0)" ::: "memory");  // retire B(p+1)
            __builtin_amdgcn_s_barrier();
        } else if (p == 14) {
            asm volatile("s_waitcnt vmcnt(0) lgkmcnt(0)" ::: "memory");
            __builtin_amdgcn_s_barrier();
        }
    }

    // ---- fused LSTM epilogue (lane-local: all 4 gates in acc[m][0..3]) ----
    const size_t HS = (size_t)NROWS * NUNITS;
    const int u = ut * 64 + q * 16 + lr;
    const float bi = bias[u],       bfg = bias[256 + u];
    const float bc = bias[512 + u], bo  = bias[768 + u];
    const float ppi = pi[u], ppf = pf[u], ppo = po[u];
    #pragma unroll
    for (int m = 0; m < 4; ++m) {
        #pragma unroll
        for (int r = 0; r < 4; ++r) {
            const int row = row0 + rh * 64 + m * 16 + hi * 4 + r;
            const size_t o = (size_t)row * NUNITS + u;
            const float cp = c_prev[o];
            float zi = acc[m][0][r] + bi  + ppi * cp;
            float zf = acc[m][1][r] + bfg + ppf * cp;
            float zc = acc[m][2][r] + bc;
            float zo = acc[m][3][r] + bo  + ppo * cp;
            float ig = 1.f / (1.f + __expf(-zi));
            float fg = 1.f / (1.f + __expf(-zf));
            float og = 1.f / (1.f + __expf(-zo));
            zc = fminf(fmaxf(zc, -30.f), 30.f);
            float e2 = __expf(2.f * zc);
            float chat = (e2 - 1.f) / (e2 + 1.f);
            float c  = fg * cp + ig * chat;
            float ccl = fminf(fmaxf(c, -30.f), 30.f);
            float e3 = __expf(2.f * ccl);
            float th = (e3 - 1.f) / (e3 + 1.f);
            float h  = og * th;
            out[o]          = h;
            out[HS + o]     = h;
            out[2 * HS + o] = c;
        }
    }
}

extern "C" void kernel_launch(void* const* d_in, const int* in_sizes, int n_in,
                              void* d_out, int out_size, void* d_ws, size_t ws_size,
                              hipStream_t stream) {
    const float* x  = (const float*)d_in[0];
    const float* h  = (const float*)d_in[1];
    const float* c  = (const float*)d_in[2];
    const float* W  = (const float*)d_in[3];
    const float* b  = (const float*)d_in[4];
    const float* pi = (const float*)d_in[5];
    const float* pf = (const float*)d_in[6];
    const float* po = (const float*)d_in[7];
    float* out = (float*)d_out;

    short* Wws = (short*)d_ws;            // 1 MiB bf16 copy of W in B-frag order

    hipLaunchKernelGGL(convert_W_kernel, dim3(2048), dim3(256), 0, stream, W, Wws);
    hipLaunchKernelGGL(lstm_main_kernel, dim3(NROWS / BM * 4), dim3(THREADS), 0, stream,
                       x, h, c, b, pi, pf, po, Wws, out);
}